// Round 4
// baseline (252.560 us; speedup 1.0000x reference)
//
#include <hip/hip_runtime.h>

#define NN 50000
#define EE 600000
#define CC 128
#define HH 8

typedef unsigned int u32;
typedef unsigned short u16;
typedef __attribute__((ext_vector_type(8))) short short8;
typedef __attribute__((ext_vector_type(4))) float f32x4;

__device__ __forceinline__ float b2f(u32 u) { return __uint_as_float(u << 16); }
__device__ __forceinline__ u16 f2b(float f) {
  u32 x = __float_as_uint(f);
  return (u16)((x + 0x7fffu + ((x >> 16) & 1u)) >> 16);
}

// workspace layout in 4-byte words
enum : int {
  OFF_FLAG = 0,
  OFF_CNT  = 64,
  OFF_OFFS = OFF_CNT + NN,
  OFF_CUR  = OFF_OFFS + NN + 64,
  OFF_WB   = OFF_CUR + NN,          // 8192 words: bf16 W[128][128]
  OFF_SL   = OFF_WB + 8192,
  OFF_SR   = OFF_SL + NN * HH,
  OFF_SSRC = OFF_SR + NN * HH,
  OFF_EMB  = OFF_SSRC + EE,         // bf16 emb: NN*64 u32 words
  WS_WORDS = OFF_EMB + NN * 64
};

// ---- prep: zero cnt, convert W->bf16, sniff edge dtype --------------------
__global__ __launch_bounds__(256) void k_prep(const int* __restrict__ ei, const float* __restrict__ W,
                                              int* __restrict__ flag, int* __restrict__ cnt,
                                              u32* __restrict__ Wb) {
  int i = blockIdx.x * 256 + threadIdx.x;
  if (i < NN) cnt[i] = 0;
  if (i < CC * CC / 2) {
    float2 v = ((const float2*)W)[i];
    Wb[i] = (u32)f2b(v.x) | ((u32)f2b(v.y) << 16);
  }
  if (blockIdx.x == 0) {
    __shared__ int any;
    if (threadIdx.x == 0) any = 0;
    __syncthreads();
    int nz = 0;
    for (int k = threadIdx.x; k < 1024; k += 256) nz |= (ei[2 * k + 1] != 0) ? 1 : 0;
    if (nz) any = 1;  // benign race
    __syncthreads();
    if (threadIdx.x == 0) flag[0] = any;  // 1 => int32 layout, 0 => int64 layout
  }
}

// ---- MFMA bf16 GEMM, BM=128, fused scores --------------------------------
#define WS_BASE 0              // bf16 W[128][128], 32 KB, XOR-swizzled
#define XS_BASE 32768          // bf16 X-tile[128][128], 32 KB, XOR-swizzled (reused for out-stage)
__device__ __forceinline__ int swz(int row, int byte_in_row) {
  return ((row * 256 + byte_in_row) ^ ((row & 7) << 4));
}

__global__ __launch_bounds__(256) void k_gemm(const float* __restrict__ X,
                                              const u32* __restrict__ Wb,
                                              const float* __restrict__ al,
                                              const float* __restrict__ ar,
                                              u32* __restrict__ emb,
                                              float* __restrict__ sl, float* __restrict__ sr) {
  __shared__ unsigned char lds[65536];
  const int tid = threadIdx.x;
  const int n0 = blockIdx.x * 128;
  const int lane = tid & 63;
  const int w = tid >> 6;
  const int cwh16 = lane & 15, kg = lane >> 4;

  // stage W (already bf16): 2048 x 16B pure copies
#pragma unroll
  for (int i = 0; i < 8; ++i) {
    int idx = tid + i * 256;
    int r = idx >> 4, c16 = idx & 15;
    uint4 v = ((const uint4*)Wb)[idx];
    *(uint4*)&lds[WS_BASE + swz(r, c16 * 16)] = v;
  }
  // stage X tile (f32 -> bf16): 128 rows x 32 float4
#pragma unroll
  for (int i = 0; i < 16; ++i) {
    int idx = tid + i * 256;
    int r = idx >> 5, c4 = idx & 31;
    int n = n0 + r;
    float4 v = make_float4(0.f, 0.f, 0.f, 0.f);
    if (n < NN) v = ((const float4*)X)[n * 32 + c4];
    u32 p0 = (u32)f2b(v.x) | ((u32)f2b(v.y) << 16);
    u32 p1 = (u32)f2b(v.z) | ((u32)f2b(v.w) << 16);
    *(uint2*)&lds[XS_BASE + swz(r, c4 * 8)] = make_uint2(p0, p1);
  }
  __syncthreads();

  f32x4 acc[2][8];
#pragma unroll
  for (int rt = 0; rt < 2; ++rt)
#pragma unroll
    for (int nt = 0; nt < 8; ++nt) acc[rt][nt] = (f32x4){0.f, 0.f, 0.f, 0.f};

#pragma unroll
  for (int kk = 0; kk < 4; ++kk) {
    const int kb = kk * 64 + kg * 16;
    short8 a0 = *(const short8*)&lds[XS_BASE + swz(w * 32 + cwh16, kb)];
    short8 a1 = *(const short8*)&lds[XS_BASE + swz(w * 32 + 16 + cwh16, kb)];
#pragma unroll
    for (int nt = 0; nt < 8; ++nt) {
      short8 b = *(const short8*)&lds[WS_BASE + swz(nt * 16 + cwh16, kb)];
      acc[0][nt] = __builtin_amdgcn_mfma_f32_16x16x32_bf16(a0, b, acc[0][nt], 0, 0, 0);
      acc[1][nt] = __builtin_amdgcn_mfma_f32_16x16x32_bf16(a1, b, acc[1][nt], 0, 0, 0);
    }
  }

  // store accumulators to LDS (bf16, swizzled) — wave w owns rows w*32..w*32+31
  __syncthreads();
#pragma unroll
  for (int rt = 0; rt < 2; ++rt)
#pragma unroll
    for (int nt = 0; nt < 8; ++nt) {
      const int col = nt * 16 + cwh16;
#pragma unroll
      for (int reg = 0; reg < 4; ++reg) {
        const int r = w * 32 + rt * 16 + kg * 4 + reg;
        *(u16*)&lds[XS_BASE + swz(r, col * 2)] = f2b(acc[rt][nt][reg]);
      }
    }
  __syncthreads();

  // fused scores from LDS emb tile: thread = (row, head-pair)
#pragma unroll
  for (int sc = 0; sc < 2; ++sc) {
    int tidx = tid + sc * 256;           // 0..511
    int r = tidx >> 2, hp = tidx & 3;
    int n = n0 + r;
    if (n < NN) {
      float sAl = 0.f, sAr = 0.f, sBl = 0.f, sBr = 0.f;
#pragma unroll
      for (int j = 0; j < 2; ++j) {      // head 2hp, cwh j*8..j*8+7
        uint4 q = *(const uint4*)&lds[XS_BASE + swz(r, hp * 64 + j * 16)];
        u32 qq[4] = {q.x, q.y, q.z, q.w};
        const int h = 2 * hp;
#pragma unroll
        for (int u = 0; u < 4; ++u) {
          int cwh = j * 8 + 2 * u;
          float lo = b2f(qq[u] & 0xffffu), hi = b2f(qq[u] >> 16);
          sAl = fmaf(lo, al[cwh * 8 + h], sAl);       sAr = fmaf(lo, ar[cwh * 8 + h], sAr);
          sAl = fmaf(hi, al[(cwh + 1) * 8 + h], sAl); sAr = fmaf(hi, ar[(cwh + 1) * 8 + h], sAr);
        }
      }
#pragma unroll
      for (int j = 0; j < 2; ++j) {      // head 2hp+1
        uint4 q = *(const uint4*)&lds[XS_BASE + swz(r, hp * 64 + 32 + j * 16)];
        u32 qq[4] = {q.x, q.y, q.z, q.w};
        const int h = 2 * hp + 1;
#pragma unroll
        for (int u = 0; u < 4; ++u) {
          int cwh = j * 8 + 2 * u;
          float lo = b2f(qq[u] & 0xffffu), hi = b2f(qq[u] >> 16);
          sBl = fmaf(lo, al[cwh * 8 + h], sBl);       sBr = fmaf(lo, ar[cwh * 8 + h], sBr);
          sBl = fmaf(hi, al[(cwh + 1) * 8 + h], sBl); sBr = fmaf(hi, ar[(cwh + 1) * 8 + h], sBr);
        }
      }
      ((float2*)&sl[n * HH])[hp] = make_float2(sAl, sBl);
      ((float2*)&sr[n * HH])[hp] = make_float2(sAr, sBr);
    }
  }

  // emb global write: 2048 x 16B coalesced
#pragma unroll
  for (int i = 0; i < 8; ++i) {
    int idx = tid + i * 256;
    int r = idx >> 4, c16 = idx & 15;
    int n = n0 + r;
    if (n < NN) {
      uint4 v = *(const uint4*)&lds[XS_BASE + swz(r, c16 * 16)];
      *((uint4*)(emb + n * 64 + c16 * 4)) = v;
    }
  }
}

// ---- CSR build ------------------------------------------------------------
__global__ __launch_bounds__(256) void k_hist(const int* __restrict__ ei, const int* __restrict__ flag,
                                              int* __restrict__ cnt) {
  int e = blockIdx.x * 256 + threadIdx.x;
  if (e >= EE) return;
  int t = flag[0] ? ei[EE + e] : ei[2 * EE + 2 * e];
  atomicAdd(&cnt[t], 1);
}

// single-block scan over 50000 counters
__global__ __launch_bounds__(1024) void k_scan(const int* __restrict__ cnt, int* __restrict__ offs,
                                               int* __restrict__ cur) {
  __shared__ int tmp[1024];
  const int t = threadIdx.x;
  const int b0 = t * 49;
  int local = 0;
  for (int i = 0; i < 49; ++i) {
    int idx = b0 + i;
    if (idx < NN) local += cnt[idx];
  }
  tmp[t] = local;
  __syncthreads();
  for (int d = 1; d < 1024; d <<= 1) {
    int x = (t >= d) ? tmp[t - d] : 0;
    __syncthreads();
    tmp[t] += x;
    __syncthreads();
  }
  int run = tmp[t] - local;   // exclusive prefix of this thread's chunk
  for (int i = 0; i < 49; ++i) {
    int idx = b0 + i;
    if (idx < NN) {
      offs[idx] = run;
      cur[idx] = run;
      run += cnt[idx];
    }
  }
  if (t == 0) offs[NN] = EE;
}

__global__ __launch_bounds__(256) void k_scatter(const int* __restrict__ ei, const int* __restrict__ flag,
                                                 int* __restrict__ cur, int* __restrict__ ssrc) {
  int e = blockIdx.x * 256 + threadIdx.x;
  if (e >= EE) return;
  int t, s;
  if (flag[0]) { s = ei[e]; t = ei[EE + e]; }
  else         { s = ei[2 * e]; t = ei[2 * EE + 2 * e]; }
  int pos = atomicAdd(&cur[t], 1);
  ssrc[pos] = s;
}

// ---- single-pass aggregation, 8/4/1 edge unroll ---------------------------
__global__ __launch_bounds__(256) void k_agg(const u32* __restrict__ emb,
                                             const float* __restrict__ sl, const float* __restrict__ sr,
                                             const int* __restrict__ offs, const int* __restrict__ ssrc,
                                             const float* __restrict__ bias, float* __restrict__ out) {
  const int t = (blockIdx.x * 256 + threadIdx.x) >> 6;
  const int lane = threadIdx.x & 63;
  if (t >= NN) return;
  const int e0 = offs[t], e1 = offs[t + 1];
  const int h2 = lane >> 3;
  const float sr2 = sr[t * HH + h2];
  float ax = 0.f, ay = 0.f, den = 0.f;
  int e = e0;
  for (; e + 8 <= e1; e += 8) {
    int s[8];
#pragma unroll
    for (int k = 0; k < 8; ++k) s[k] = ssrc[e + k];
    float v[8];
    u32 p[8];
#pragma unroll
    for (int k = 0; k < 8; ++k) v[k] = sl[s[k] * HH + h2];
#pragma unroll
    for (int k = 0; k < 8; ++k) p[k] = emb[s[k] * 64 + lane];
#pragma unroll
    for (int k = 0; k < 8; ++k) {
      float vv = v[k] + sr2;
      vv = (vv > 0.f) ? vv : 0.2f * vv;
      float wgt = __expf(vv);
      den += wgt;
      ax = fmaf(wgt, b2f(p[k] & 0xffffu), ax);
      ay = fmaf(wgt, b2f(p[k] >> 16), ay);
    }
  }
  for (; e + 4 <= e1; e += 4) {
    int s[4];
#pragma unroll
    for (int k = 0; k < 4; ++k) s[k] = ssrc[e + k];
    float v[4];
    u32 p[4];
#pragma unroll
    for (int k = 0; k < 4; ++k) v[k] = sl[s[k] * HH + h2];
#pragma unroll
    for (int k = 0; k < 4; ++k) p[k] = emb[s[k] * 64 + lane];
#pragma unroll
    for (int k = 0; k < 4; ++k) {
      float vv = v[k] + sr2;
      vv = (vv > 0.f) ? vv : 0.2f * vv;
      float wgt = __expf(vv);
      den += wgt;
      ax = fmaf(wgt, b2f(p[k] & 0xffffu), ax);
      ay = fmaf(wgt, b2f(p[k] >> 16), ay);
    }
  }
  for (; e < e1; ++e) {
    int s = ssrc[e];
    float vv = sl[s * HH + h2] + sr2;
    vv = (vv > 0.f) ? vv : 0.2f * vv;
    float wgt = __expf(vv);
    den += wgt;
    u32 p = emb[s * 64 + lane];
    ax = fmaf(wgt, b2f(p & 0xffffu), ax);
    ay = fmaf(wgt, b2f(p >> 16), ay);
  }
  const float inv = 1.f / (den + 1e-16f);
  float2 bv = ((const float2*)bias)[lane];
  ((float2*)out)[t * 64 + lane] = make_float2(fmaf(ax, inv, bv.x), fmaf(ay, inv, bv.y));
}

extern "C" void kernel_launch(void* const* d_in, const int* in_sizes, int n_in,
                              void* d_out, int out_size, void* d_ws, size_t ws_size,
                              hipStream_t stream) {
  const float* X  = (const float*)d_in[0];
  const int*   EI = (const int*)d_in[1];
  const float* W  = (const float*)d_in[2];
  const float* AL = (const float*)d_in[3];
  const float* AR = (const float*)d_in[4];
  const float* B  = (const float*)d_in[5];
  float* out = (float*)d_out;
  u32* ws = (u32*)d_ws;

  int*   flag = (int*)(ws + OFF_FLAG);
  int*   cnt  = (int*)(ws + OFF_CNT);
  int*   offs = (int*)(ws + OFF_OFFS);
  int*   cur  = (int*)(ws + OFF_CUR);
  u32*   Wb   = (u32*)(ws + OFF_WB);
  float* sl   = (float*)(ws + OFF_SL);
  float* sr   = (float*)(ws + OFF_SR);
  int*   ssrc = (int*)(ws + OFF_SSRC);
  u32*   emb  = (u32*)(ws + OFF_EMB);

  const int nbN = (NN + 255) / 256;     // 196
  const int nbE = (EE + 255) / 256;     // 2344

  k_prep<<<nbN, 256, 0, stream>>>(EI, W, flag, cnt, Wb);
  k_gemm<<<(NN + 127) / 128, 256, 0, stream>>>(X, Wb, AL, AR, emb, sl, sr);
  k_hist<<<nbE, 256, 0, stream>>>(EI, flag, cnt);
  k_scan<<<1, 1024, 0, stream>>>(cnt, offs, cur);
  k_scatter<<<nbE, 256, 0, stream>>>(EI, flag, cur, ssrc);
  k_agg<<<(NN * 64 + 255) / 256, 256, 0, stream>>>(emb, sl, sr, offs, ssrc, B, out);
}

// Round 5
// 135.559 us; speedup vs baseline: 1.8631x; 1.8631x over previous
//
#include <hip/hip_runtime.h>

#define NN 50000
#define EE 600000
#define CC 128
#define HH 8

typedef unsigned int u32;
typedef unsigned short u16;
typedef __attribute__((ext_vector_type(8))) short short8;
typedef __attribute__((ext_vector_type(4))) float f32x4;

__device__ __forceinline__ float b2f(u32 u) { return __uint_as_float(u << 16); }
__device__ __forceinline__ u16 f2b(float f) {
  u32 x = __float_as_uint(f);
  return (u16)((x + 0x7fffu + ((x >> 16) & 1u)) >> 16);
}

// workspace layout in 4-byte words
enum : int {
  OFF_FLAG = 0,
  OFF_CNT  = 64,
  OFF_OFFS = OFF_CNT + NN,
  OFF_CUR  = OFF_OFFS + NN + 64,
  OFF_BSUM = OFF_CUR + NN,          // 256 words
  OFF_WB   = OFF_BSUM + 256,        // 8192 words: bf16 W[128][128]
  OFF_SL   = OFF_WB + 8192,
  OFF_SR   = OFF_SL + NN * HH,
  OFF_SSRC = OFF_SR + NN * HH,
  OFF_EMB  = OFF_SSRC + EE,         // bf16 emb: NN*64 u32 words
  WS_WORDS = OFF_EMB + NN * 64
};

// ---- prep: zero cnt, convert W->bf16, sniff edge dtype --------------------
__global__ __launch_bounds__(256) void k_prep(const int* __restrict__ ei, const float* __restrict__ W,
                                              int* __restrict__ flag, int* __restrict__ cnt,
                                              u32* __restrict__ Wb) {
  int i = blockIdx.x * 256 + threadIdx.x;
  if (i < NN) cnt[i] = 0;
  if (i < CC * CC / 2) {
    float2 v = ((const float2*)W)[i];
    Wb[i] = (u32)f2b(v.x) | ((u32)f2b(v.y) << 16);
  }
  if (blockIdx.x == 0) {
    __shared__ int any;
    if (threadIdx.x == 0) any = 0;
    __syncthreads();
    int nz = 0;
    for (int k = threadIdx.x; k < 1024; k += 256) nz |= (ei[2 * k + 1] != 0) ? 1 : 0;
    if (nz) any = 1;  // benign race
    __syncthreads();
    if (threadIdx.x == 0) flag[0] = any;  // 1 => int32 layout, 0 => int64 layout
  }
}

// ---- MFMA bf16 GEMM, BM=128, fused scores --------------------------------
#define WS_BASE 0              // bf16 W[128][128], 32 KB, XOR-swizzled
#define XS_BASE 32768          // bf16 X-tile[128][128], 32 KB, XOR-swizzled (reused for out-stage)
__device__ __forceinline__ int swz(int row, int byte_in_row) {
  return ((row * 256 + byte_in_row) ^ ((row & 7) << 4));
}

__global__ __launch_bounds__(256) void k_gemm(const float* __restrict__ X,
                                              const u32* __restrict__ Wb,
                                              const float* __restrict__ al,
                                              const float* __restrict__ ar,
                                              u32* __restrict__ emb,
                                              float* __restrict__ sl, float* __restrict__ sr) {
  __shared__ unsigned char lds[65536];
  const int tid = threadIdx.x;
  const int n0 = blockIdx.x * 128;
  const int lane = tid & 63;
  const int w = tid >> 6;
  const int cwh16 = lane & 15, kg = lane >> 4;

  // stage W (already bf16): 2048 x 16B pure copies
#pragma unroll
  for (int i = 0; i < 8; ++i) {
    int idx = tid + i * 256;
    int r = idx >> 4, c16 = idx & 15;
    uint4 v = ((const uint4*)Wb)[idx];
    *(uint4*)&lds[WS_BASE + swz(r, c16 * 16)] = v;
  }
  // stage X tile (f32 -> bf16): 128 rows x 32 float4
#pragma unroll
  for (int i = 0; i < 16; ++i) {
    int idx = tid + i * 256;
    int r = idx >> 5, c4 = idx & 31;
    int n = n0 + r;
    float4 v = make_float4(0.f, 0.f, 0.f, 0.f);
    if (n < NN) v = ((const float4*)X)[n * 32 + c4];
    u32 p0 = (u32)f2b(v.x) | ((u32)f2b(v.y) << 16);
    u32 p1 = (u32)f2b(v.z) | ((u32)f2b(v.w) << 16);
    *(uint2*)&lds[XS_BASE + swz(r, c4 * 8)] = make_uint2(p0, p1);
  }
  __syncthreads();

  f32x4 acc[2][8];
#pragma unroll
  for (int rt = 0; rt < 2; ++rt)
#pragma unroll
    for (int nt = 0; nt < 8; ++nt) acc[rt][nt] = (f32x4){0.f, 0.f, 0.f, 0.f};

#pragma unroll
  for (int kk = 0; kk < 4; ++kk) {
    const int kb = kk * 64 + kg * 16;
    short8 a0 = *(const short8*)&lds[XS_BASE + swz(w * 32 + cwh16, kb)];
    short8 a1 = *(const short8*)&lds[XS_BASE + swz(w * 32 + 16 + cwh16, kb)];
#pragma unroll
    for (int nt = 0; nt < 8; ++nt) {
      short8 b = *(const short8*)&lds[WS_BASE + swz(nt * 16 + cwh16, kb)];
      acc[0][nt] = __builtin_amdgcn_mfma_f32_16x16x32_bf16(a0, b, acc[0][nt], 0, 0, 0);
      acc[1][nt] = __builtin_amdgcn_mfma_f32_16x16x32_bf16(a1, b, acc[1][nt], 0, 0, 0);
    }
  }

  // store accumulators to LDS (bf16, swizzled) — wave w owns rows w*32..w*32+31
  __syncthreads();
#pragma unroll
  for (int rt = 0; rt < 2; ++rt)
#pragma unroll
    for (int nt = 0; nt < 8; ++nt) {
      const int col = nt * 16 + cwh16;
#pragma unroll
      for (int reg = 0; reg < 4; ++reg) {
        const int r = w * 32 + rt * 16 + kg * 4 + reg;
        *(u16*)&lds[XS_BASE + swz(r, col * 2)] = f2b(acc[rt][nt][reg]);
      }
    }
  __syncthreads();

  // fused scores from LDS emb tile: thread = (row, head-pair)
#pragma unroll
  for (int sc = 0; sc < 2; ++sc) {
    int tidx = tid + sc * 256;           // 0..511
    int r = tidx >> 2, hp = tidx & 3;
    int n = n0 + r;
    if (n < NN) {
      float sAl = 0.f, sAr = 0.f, sBl = 0.f, sBr = 0.f;
#pragma unroll
      for (int j = 0; j < 2; ++j) {      // head 2hp, cwh j*8..j*8+7
        uint4 q = *(const uint4*)&lds[XS_BASE + swz(r, hp * 64 + j * 16)];
        u32 qq[4] = {q.x, q.y, q.z, q.w};
        const int h = 2 * hp;
#pragma unroll
        for (int u = 0; u < 4; ++u) {
          int cwh = j * 8 + 2 * u;
          float lo = b2f(qq[u] & 0xffffu), hi = b2f(qq[u] >> 16);
          sAl = fmaf(lo, al[cwh * 8 + h], sAl);       sAr = fmaf(lo, ar[cwh * 8 + h], sAr);
          sAl = fmaf(hi, al[(cwh + 1) * 8 + h], sAl); sAr = fmaf(hi, ar[(cwh + 1) * 8 + h], sAr);
        }
      }
#pragma unroll
      for (int j = 0; j < 2; ++j) {      // head 2hp+1
        uint4 q = *(const uint4*)&lds[XS_BASE + swz(r, hp * 64 + 32 + j * 16)];
        u32 qq[4] = {q.x, q.y, q.z, q.w};
        const int h = 2 * hp + 1;
#pragma unroll
        for (int u = 0; u < 4; ++u) {
          int cwh = j * 8 + 2 * u;
          float lo = b2f(qq[u] & 0xffffu), hi = b2f(qq[u] >> 16);
          sBl = fmaf(lo, al[cwh * 8 + h], sBl);       sBr = fmaf(lo, ar[cwh * 8 + h], sBr);
          sBl = fmaf(hi, al[(cwh + 1) * 8 + h], sBl); sBr = fmaf(hi, ar[(cwh + 1) * 8 + h], sBr);
        }
      }
      ((float2*)&sl[n * HH])[hp] = make_float2(sAl, sBl);
      ((float2*)&sr[n * HH])[hp] = make_float2(sAr, sBr);
    }
  }

  // emb global write: 2048 x 16B coalesced
#pragma unroll
  for (int i = 0; i < 8; ++i) {
    int idx = tid + i * 256;
    int r = idx >> 4, c16 = idx & 15;
    int n = n0 + r;
    if (n < NN) {
      uint4 v = *(const uint4*)&lds[XS_BASE + swz(r, c16 * 16)];
      *((uint4*)(emb + n * 64 + c16 * 4)) = v;
    }
  }
}

// ---- CSR build ------------------------------------------------------------
__global__ __launch_bounds__(256) void k_hist(const int* __restrict__ ei, const int* __restrict__ flag,
                                              int* __restrict__ cnt) {
  int e = blockIdx.x * 256 + threadIdx.x;
  if (e >= EE) return;
  int t = flag[0] ? ei[EE + e] : ei[2 * EE + 2 * e];
  atomicAdd(&cnt[t], 1);
}

__global__ __launch_bounds__(256) void k_scanA(const int* __restrict__ cnt, int* __restrict__ offs,
                                               int* __restrict__ bsum) {
  __shared__ int tmp[256];
  const int t = threadIdx.x;
  const int i = blockIdx.x * 256 + t;
  int v = (i < NN) ? cnt[i] : 0;
  tmp[t] = v;
  __syncthreads();
#pragma unroll
  for (int d = 1; d < 256; d <<= 1) {
    int x = (t >= d) ? tmp[t - d] : 0;
    __syncthreads();
    tmp[t] += x;
    __syncthreads();
  }
  if (i < NN) offs[i] = tmp[t] - v;      // block-local exclusive
  if (t == 255) bsum[blockIdx.x] = tmp[255];
}

__global__ __launch_bounds__(256) void k_scanB(int* __restrict__ bsum, int nb) {
  __shared__ int tmp[256];
  const int t = threadIdx.x;
  int v = (t < nb) ? bsum[t] : 0;
  tmp[t] = v;
  __syncthreads();
#pragma unroll
  for (int d = 1; d < 256; d <<= 1) {
    int x = (t >= d) ? tmp[t - d] : 0;
    __syncthreads();
    tmp[t] += x;
    __syncthreads();
  }
  if (t < nb) bsum[t] = tmp[t] - v;      // exclusive
}

__global__ __launch_bounds__(256) void k_scanC(const int* __restrict__ bsum, int* __restrict__ offs,
                                               int* __restrict__ cur) {
  const int i = blockIdx.x * 256 + threadIdx.x;
  if (i < NN) {
    int o = offs[i] + bsum[blockIdx.x];
    offs[i] = o;
    cur[i] = o;
  }
  if (i == 0) offs[NN] = EE;
}

__global__ __launch_bounds__(256) void k_scatter(const int* __restrict__ ei, const int* __restrict__ flag,
                                                 int* __restrict__ cur, int* __restrict__ ssrc) {
  int e = blockIdx.x * 256 + threadIdx.x;
  if (e >= EE) return;
  int t, s;
  if (flag[0]) { s = ei[e]; t = ei[EE + e]; }
  else         { s = ei[2 * e]; t = ei[2 * EE + 2 * e]; }
  int pos = atomicAdd(&cur[t], 1);
  ssrc[pos] = s;
}

// ---- single-pass aggregation, 8/4/1 edge unroll ---------------------------
__global__ __launch_bounds__(256) void k_agg(const u32* __restrict__ emb,
                                             const float* __restrict__ sl, const float* __restrict__ sr,
                                             const int* __restrict__ offs, const int* __restrict__ ssrc,
                                             const float* __restrict__ bias, float* __restrict__ out) {
  const int t = (blockIdx.x * 256 + threadIdx.x) >> 6;
  const int lane = threadIdx.x & 63;
  if (t >= NN) return;
  const int e0 = offs[t], e1 = offs[t + 1];
  const int h2 = lane >> 3;
  const float sr2 = sr[t * HH + h2];
  float ax = 0.f, ay = 0.f, den = 0.f;
  int e = e0;
  for (; e + 8 <= e1; e += 8) {
    int s[8];
#pragma unroll
    for (int k = 0; k < 8; ++k) s[k] = ssrc[e + k];
    float v[8];
    u32 p[8];
#pragma unroll
    for (int k = 0; k < 8; ++k) v[k] = sl[s[k] * HH + h2];
#pragma unroll
    for (int k = 0; k < 8; ++k) p[k] = emb[s[k] * 64 + lane];
#pragma unroll
    for (int k = 0; k < 8; ++k) {
      float vv = v[k] + sr2;
      vv = (vv > 0.f) ? vv : 0.2f * vv;
      float wgt = __expf(vv);
      den += wgt;
      ax = fmaf(wgt, b2f(p[k] & 0xffffu), ax);
      ay = fmaf(wgt, b2f(p[k] >> 16), ay);
    }
  }
  for (; e + 4 <= e1; e += 4) {
    int s[4];
#pragma unroll
    for (int k = 0; k < 4; ++k) s[k] = ssrc[e + k];
    float v[4];
    u32 p[4];
#pragma unroll
    for (int k = 0; k < 4; ++k) v[k] = sl[s[k] * HH + h2];
#pragma unroll
    for (int k = 0; k < 4; ++k) p[k] = emb[s[k] * 64 + lane];
#pragma unroll
    for (int k = 0; k < 4; ++k) {
      float vv = v[k] + sr2;
      vv = (vv > 0.f) ? vv : 0.2f * vv;
      float wgt = __expf(vv);
      den += wgt;
      ax = fmaf(wgt, b2f(p[k] & 0xffffu), ax);
      ay = fmaf(wgt, b2f(p[k] >> 16), ay);
    }
  }
  for (; e < e1; ++e) {
    int s = ssrc[e];
    float vv = sl[s * HH + h2] + sr2;
    vv = (vv > 0.f) ? vv : 0.2f * vv;
    float wgt = __expf(vv);
    den += wgt;
    u32 p = emb[s * 64 + lane];
    ax = fmaf(wgt, b2f(p & 0xffffu), ax);
    ay = fmaf(wgt, b2f(p >> 16), ay);
  }
  const float inv = 1.f / (den + 1e-16f);
  float2 bv = ((const float2*)bias)[lane];
  ((float2*)out)[t * 64 + lane] = make_float2(fmaf(ax, inv, bv.x), fmaf(ay, inv, bv.y));
}

extern "C" void kernel_launch(void* const* d_in, const int* in_sizes, int n_in,
                              void* d_out, int out_size, void* d_ws, size_t ws_size,
                              hipStream_t stream) {
  const float* X  = (const float*)d_in[0];
  const int*   EI = (const int*)d_in[1];
  const float* W  = (const float*)d_in[2];
  const float* AL = (const float*)d_in[3];
  const float* AR = (const float*)d_in[4];
  const float* B  = (const float*)d_in[5];
  float* out = (float*)d_out;
  u32* ws = (u32*)d_ws;

  int*   flag = (int*)(ws + OFF_FLAG);
  int*   cnt  = (int*)(ws + OFF_CNT);
  int*   offs = (int*)(ws + OFF_OFFS);
  int*   cur  = (int*)(ws + OFF_CUR);
  int*   bsum = (int*)(ws + OFF_BSUM);
  u32*   Wb   = (u32*)(ws + OFF_WB);
  float* sl   = (float*)(ws + OFF_SL);
  float* sr   = (float*)(ws + OFF_SR);
  int*   ssrc = (int*)(ws + OFF_SSRC);
  u32*   emb  = (u32*)(ws + OFF_EMB);

  const int nbN = (NN + 255) / 256;     // 196
  const int nbE = (EE + 255) / 256;     // 2344

  k_prep<<<nbN, 256, 0, stream>>>(EI, W, flag, cnt, Wb);
  k_gemm<<<(NN + 127) / 128, 256, 0, stream>>>(X, Wb, AL, AR, emb, sl, sr);
  k_hist<<<nbE, 256, 0, stream>>>(EI, flag, cnt);
  k_scanA<<<nbN, 256, 0, stream>>>(cnt, offs, bsum);
  k_scanB<<<1, 256, 0, stream>>>(bsum, nbN);
  k_scanC<<<nbN, 256, 0, stream>>>(bsum, offs, cur);
  k_scatter<<<nbE, 256, 0, stream>>>(EI, flag, cur, ssrc);
  k_agg<<<(NN * 64 + 255) / 256, 256, 0, stream>>>(emb, sl, sr, offs, ssrc, B, out);
}

// Round 6
// 132.326 us; speedup vs baseline: 1.9086x; 1.0244x over previous
//
#include <hip/hip_runtime.h>

#define NN 50000
#define EE 600000
#define CC 128
#define HH 8
#define ESTRIDE 150000   // EE/4: edges per grid-stride pass

typedef unsigned int u32;
typedef unsigned short u16;
typedef __attribute__((ext_vector_type(8))) short short8;
typedef __attribute__((ext_vector_type(4))) float f32x4;

__device__ __forceinline__ float b2f(u32 u) { return __uint_as_float(u << 16); }
__device__ __forceinline__ u16 f2b(float f) {
  u32 x = __float_as_uint(f);
  return (u16)((x + 0x7fffu + ((x >> 16) & 1u)) >> 16);
}

// workspace layout in 4-byte words
enum : int {
  OFF_FLAG = 0,
  OFF_CNT  = 64,
  OFF_OFFS = OFF_CNT + NN,
  OFF_CUR  = OFF_OFFS + NN + 64,
  OFF_BSUM = OFF_CUR + NN,          // 256 words
  OFF_WB   = OFF_BSUM + 256,        // 8192 words: bf16 W[128][128]
  OFF_SL   = OFF_WB + 8192,
  OFF_SR   = OFF_SL + NN * HH,
  OFF_SSRC = OFF_SR + NN * HH,
  OFF_EMB  = OFF_SSRC + EE,         // bf16 emb: NN*64 u32 words
  WS_WORDS = OFF_EMB + NN * 64
};

// ---- prep: zero cnt, convert W->bf16, sniff edge dtype --------------------
__global__ __launch_bounds__(256) void k_prep(const int* __restrict__ ei, const float* __restrict__ W,
                                              int* __restrict__ flag, int* __restrict__ cnt,
                                              u32* __restrict__ Wb) {
  int i = blockIdx.x * 256 + threadIdx.x;
  if (i < NN) cnt[i] = 0;
  if (i < CC * CC / 2) {
    float2 v = ((const float2*)W)[i];
    Wb[i] = (u32)f2b(v.x) | ((u32)f2b(v.y) << 16);
  }
  if (blockIdx.x == 0) {
    __shared__ int any;
    if (threadIdx.x == 0) any = 0;
    __syncthreads();
    int nz = 0;
    for (int k = threadIdx.x; k < 1024; k += 256) nz |= (ei[2 * k + 1] != 0) ? 1 : 0;
    if (nz) any = 1;  // benign race
    __syncthreads();
    if (threadIdx.x == 0) flag[0] = any;  // 1 => int32 layout, 0 => int64 layout
  }
}

// ---- MFMA bf16 GEMM, BM=128, fused scores --------------------------------
#define WS_BASE 0              // bf16 W[128][128], 32 KB, XOR-swizzled
#define XS_BASE 32768          // bf16 X-tile[128][128], 32 KB, XOR-swizzled (reused for out-stage)
__device__ __forceinline__ int swz(int row, int byte_in_row) {
  return ((row * 256 + byte_in_row) ^ ((row & 7) << 4));
}

__global__ __launch_bounds__(256) void k_gemm(const float* __restrict__ X,
                                              const u32* __restrict__ Wb,
                                              const float* __restrict__ al,
                                              const float* __restrict__ ar,
                                              u32* __restrict__ emb,
                                              float* __restrict__ sl, float* __restrict__ sr) {
  __shared__ unsigned char lds[65536];
  const int tid = threadIdx.x;
  const int n0 = blockIdx.x * 128;
  const int lane = tid & 63;
  const int w = tid >> 6;
  const int cwh16 = lane & 15, kg = lane >> 4;

  // stage W (already bf16): 2048 x 16B pure copies
#pragma unroll
  for (int i = 0; i < 8; ++i) {
    int idx = tid + i * 256;
    int r = idx >> 4, c16 = idx & 15;
    uint4 v = ((const uint4*)Wb)[idx];
    *(uint4*)&lds[WS_BASE + swz(r, c16 * 16)] = v;
  }
  // stage X tile (f32 -> bf16): 128 rows x 32 float4
#pragma unroll
  for (int i = 0; i < 16; ++i) {
    int idx = tid + i * 256;
    int r = idx >> 5, c4 = idx & 31;
    int n = n0 + r;
    float4 v = make_float4(0.f, 0.f, 0.f, 0.f);
    if (n < NN) v = ((const float4*)X)[n * 32 + c4];
    u32 p0 = (u32)f2b(v.x) | ((u32)f2b(v.y) << 16);
    u32 p1 = (u32)f2b(v.z) | ((u32)f2b(v.w) << 16);
    *(uint2*)&lds[XS_BASE + swz(r, c4 * 8)] = make_uint2(p0, p1);
  }
  __syncthreads();

  f32x4 acc[2][8];
#pragma unroll
  for (int rt = 0; rt < 2; ++rt)
#pragma unroll
    for (int nt = 0; nt < 8; ++nt) acc[rt][nt] = (f32x4){0.f, 0.f, 0.f, 0.f};

#pragma unroll
  for (int kk = 0; kk < 4; ++kk) {
    const int kb = kk * 64 + kg * 16;
    short8 a0 = *(const short8*)&lds[XS_BASE + swz(w * 32 + cwh16, kb)];
    short8 a1 = *(const short8*)&lds[XS_BASE + swz(w * 32 + 16 + cwh16, kb)];
#pragma unroll
    for (int nt = 0; nt < 8; ++nt) {
      short8 b = *(const short8*)&lds[WS_BASE + swz(nt * 16 + cwh16, kb)];
      acc[0][nt] = __builtin_amdgcn_mfma_f32_16x16x32_bf16(a0, b, acc[0][nt], 0, 0, 0);
      acc[1][nt] = __builtin_amdgcn_mfma_f32_16x16x32_bf16(a1, b, acc[1][nt], 0, 0, 0);
    }
  }

  // store accumulators to LDS (bf16, swizzled) — wave w owns rows w*32..w*32+31
  __syncthreads();
#pragma unroll
  for (int rt = 0; rt < 2; ++rt)
#pragma unroll
    for (int nt = 0; nt < 8; ++nt) {
      const int col = nt * 16 + cwh16;
#pragma unroll
      for (int reg = 0; reg < 4; ++reg) {
        const int r = w * 32 + rt * 16 + kg * 4 + reg;
        *(u16*)&lds[XS_BASE + swz(r, col * 2)] = f2b(acc[rt][nt][reg]);
      }
    }
  __syncthreads();

  // fused scores from LDS emb tile: thread = (row, head-pair)
#pragma unroll
  for (int sc = 0; sc < 2; ++sc) {
    int tidx = tid + sc * 256;           // 0..511
    int r = tidx >> 2, hp = tidx & 3;
    int n = n0 + r;
    if (n < NN) {
      float sAl = 0.f, sAr = 0.f, sBl = 0.f, sBr = 0.f;
#pragma unroll
      for (int j = 0; j < 2; ++j) {      // head 2hp, cwh j*8..j*8+7
        uint4 q = *(const uint4*)&lds[XS_BASE + swz(r, hp * 64 + j * 16)];
        u32 qq[4] = {q.x, q.y, q.z, q.w};
        const int h = 2 * hp;
#pragma unroll
        for (int u = 0; u < 4; ++u) {
          int cwh = j * 8 + 2 * u;
          float lo = b2f(qq[u] & 0xffffu), hi = b2f(qq[u] >> 16);
          sAl = fmaf(lo, al[cwh * 8 + h], sAl);       sAr = fmaf(lo, ar[cwh * 8 + h], sAr);
          sAl = fmaf(hi, al[(cwh + 1) * 8 + h], sAl); sAr = fmaf(hi, ar[(cwh + 1) * 8 + h], sAr);
        }
      }
#pragma unroll
      for (int j = 0; j < 2; ++j) {      // head 2hp+1
        uint4 q = *(const uint4*)&lds[XS_BASE + swz(r, hp * 64 + 32 + j * 16)];
        u32 qq[4] = {q.x, q.y, q.z, q.w};
        const int h = 2 * hp + 1;
#pragma unroll
        for (int u = 0; u < 4; ++u) {
          int cwh = j * 8 + 2 * u;
          float lo = b2f(qq[u] & 0xffffu), hi = b2f(qq[u] >> 16);
          sBl = fmaf(lo, al[cwh * 8 + h], sBl);       sBr = fmaf(lo, ar[cwh * 8 + h], sBr);
          sBl = fmaf(hi, al[(cwh + 1) * 8 + h], sBl); sBr = fmaf(hi, ar[(cwh + 1) * 8 + h], sBr);
        }
      }
      ((float2*)&sl[n * HH])[hp] = make_float2(sAl, sBl);
      ((float2*)&sr[n * HH])[hp] = make_float2(sAr, sBr);
    }
  }

  // emb global write: 2048 x 16B coalesced
#pragma unroll
  for (int i = 0; i < 8; ++i) {
    int idx = tid + i * 256;
    int r = idx >> 4, c16 = idx & 15;
    int n = n0 + r;
    if (n < NN) {
      uint4 v = *(const uint4*)&lds[XS_BASE + swz(r, c16 * 16)];
      *((uint4*)(emb + n * 64 + c16 * 4)) = v;
    }
  }
}

// ---- CSR build: 4 edges/thread, independent atomic chains -----------------
__global__ __launch_bounds__(256) void k_hist(const int* __restrict__ ei, const int* __restrict__ flag,
                                              int* __restrict__ cnt) {
  const int tid = blockIdx.x * 256 + threadIdx.x;
  if (tid >= ESTRIDE) return;
  const int f = flag[0];
  int t[4];
  if (f) {
#pragma unroll
    for (int k = 0; k < 4; ++k) t[k] = ei[EE + tid + k * ESTRIDE];
  } else {
#pragma unroll
    for (int k = 0; k < 4; ++k) t[k] = ((const int2*)ei)[EE + tid + k * ESTRIDE].x;
  }
#pragma unroll
  for (int k = 0; k < 4; ++k) atomicAdd(&cnt[t[k]], 1);
}

__global__ __launch_bounds__(256) void k_scanA(const int* __restrict__ cnt, int* __restrict__ offs,
                                               int* __restrict__ bsum) {
  __shared__ int tmp[256];
  const int t = threadIdx.x;
  const int i = blockIdx.x * 256 + t;
  int v = (i < NN) ? cnt[i] : 0;
  tmp[t] = v;
  __syncthreads();
#pragma unroll
  for (int d = 1; d < 256; d <<= 1) {
    int x = (t >= d) ? tmp[t - d] : 0;
    __syncthreads();
    tmp[t] += x;
    __syncthreads();
  }
  if (i < NN) offs[i] = tmp[t] - v;      // block-local exclusive
  if (t == 255) bsum[blockIdx.x] = tmp[255];
}

__global__ __launch_bounds__(256) void k_scanB(int* __restrict__ bsum, int nb) {
  __shared__ int tmp[256];
  const int t = threadIdx.x;
  int v = (t < nb) ? bsum[t] : 0;
  tmp[t] = v;
  __syncthreads();
#pragma unroll
  for (int d = 1; d < 256; d <<= 1) {
    int x = (t >= d) ? tmp[t - d] : 0;
    __syncthreads();
    tmp[t] += x;
    __syncthreads();
  }
  if (t < nb) bsum[t] = tmp[t] - v;      // exclusive
}

__global__ __launch_bounds__(256) void k_scanC(const int* __restrict__ bsum, int* __restrict__ offs,
                                               int* __restrict__ cur) {
  const int i = blockIdx.x * 256 + threadIdx.x;
  if (i < NN) {
    int o = offs[i] + bsum[blockIdx.x];
    offs[i] = o;
    cur[i] = o;
  }
  if (i == 0) offs[NN] = EE;
}

__global__ __launch_bounds__(256) void k_scatter(const int* __restrict__ ei, const int* __restrict__ flag,
                                                 int* __restrict__ cur, int* __restrict__ ssrc) {
  const int tid = blockIdx.x * 256 + threadIdx.x;
  if (tid >= ESTRIDE) return;
  const int f = flag[0];
  int s[4], t[4];
  if (f) {
#pragma unroll
    for (int k = 0; k < 4; ++k) {
      s[k] = ei[tid + k * ESTRIDE];
      t[k] = ei[EE + tid + k * ESTRIDE];
    }
  } else {
#pragma unroll
    for (int k = 0; k < 4; ++k) {
      s[k] = ((const int2*)ei)[tid + k * ESTRIDE].x;
      t[k] = ((const int2*)ei)[EE + tid + k * ESTRIDE].x;
    }
  }
  int pos[4];
#pragma unroll
  for (int k = 0; k < 4; ++k) pos[k] = atomicAdd(&cur[t[k]], 1);
#pragma unroll
  for (int k = 0; k < 4; ++k) ssrc[pos[k]] = s[k];
}

// ---- single-pass aggregation, 8/4/1 edge unroll ---------------------------
__global__ __launch_bounds__(256) void k_agg(const u32* __restrict__ emb,
                                             const float* __restrict__ sl, const float* __restrict__ sr,
                                             const int* __restrict__ offs, const int* __restrict__ ssrc,
                                             const float* __restrict__ bias, float* __restrict__ out) {
  const int t = (blockIdx.x * 256 + threadIdx.x) >> 6;
  const int lane = threadIdx.x & 63;
  if (t >= NN) return;
  const int e0 = offs[t], e1 = offs[t + 1];
  const int h2 = lane >> 3;
  const float sr2 = sr[t * HH + h2];
  float ax = 0.f, ay = 0.f, den = 0.f;
  int e = e0;
  for (; e + 8 <= e1; e += 8) {
    int s[8];
#pragma unroll
    for (int k = 0; k < 8; ++k) s[k] = ssrc[e + k];
    float v[8];
    u32 p[8];
#pragma unroll
    for (int k = 0; k < 8; ++k) v[k] = sl[s[k] * HH + h2];
#pragma unroll
    for (int k = 0; k < 8; ++k) p[k] = emb[s[k] * 64 + lane];
#pragma unroll
    for (int k = 0; k < 8; ++k) {
      float vv = v[k] + sr2;
      vv = (vv > 0.f) ? vv : 0.2f * vv;
      float wgt = __expf(vv);
      den += wgt;
      ax = fmaf(wgt, b2f(p[k] & 0xffffu), ax);
      ay = fmaf(wgt, b2f(p[k] >> 16), ay);
    }
  }
  for (; e + 4 <= e1; e += 4) {
    int s[4];
#pragma unroll
    for (int k = 0; k < 4; ++k) s[k] = ssrc[e + k];
    float v[4];
    u32 p[4];
#pragma unroll
    for (int k = 0; k < 4; ++k) v[k] = sl[s[k] * HH + h2];
#pragma unroll
    for (int k = 0; k < 4; ++k) p[k] = emb[s[k] * 64 + lane];
#pragma unroll
    for (int k = 0; k < 4; ++k) {
      float vv = v[k] + sr2;
      vv = (vv > 0.f) ? vv : 0.2f * vv;
      float wgt = __expf(vv);
      den += wgt;
      ax = fmaf(wgt, b2f(p[k] & 0xffffu), ax);
      ay = fmaf(wgt, b2f(p[k] >> 16), ay);
    }
  }
  for (; e < e1; ++e) {
    int s = ssrc[e];
    float vv = sl[s * HH + h2] + sr2;
    vv = (vv > 0.f) ? vv : 0.2f * vv;
    float wgt = __expf(vv);
    den += wgt;
    u32 p = emb[s * 64 + lane];
    ax = fmaf(wgt, b2f(p & 0xffffu), ax);
    ay = fmaf(wgt, b2f(p >> 16), ay);
  }
  const float inv = 1.f / (den + 1e-16f);
  float2 bv = ((const float2*)bias)[lane];
  ((float2*)out)[t * 64 + lane] = make_float2(fmaf(ax, inv, bv.x), fmaf(ay, inv, bv.y));
}

extern "C" void kernel_launch(void* const* d_in, const int* in_sizes, int n_in,
                              void* d_out, int out_size, void* d_ws, size_t ws_size,
                              hipStream_t stream) {
  const float* X  = (const float*)d_in[0];
  const int*   EI = (const int*)d_in[1];
  const float* W  = (const float*)d_in[2];
  const float* AL = (const float*)d_in[3];
  const float* AR = (const float*)d_in[4];
  const float* B  = (const float*)d_in[5];
  float* out = (float*)d_out;
  u32* ws = (u32*)d_ws;

  int*   flag = (int*)(ws + OFF_FLAG);
  int*   cnt  = (int*)(ws + OFF_CNT);
  int*   offs = (int*)(ws + OFF_OFFS);
  int*   cur  = (int*)(ws + OFF_CUR);
  int*   bsum = (int*)(ws + OFF_BSUM);
  u32*   Wb   = (u32*)(ws + OFF_WB);
  float* sl   = (float*)(ws + OFF_SL);
  float* sr   = (float*)(ws + OFF_SR);
  int*   ssrc = (int*)(ws + OFF_SSRC);
  u32*   emb  = (u32*)(ws + OFF_EMB);

  const int nbN = (NN + 255) / 256;     // 196
  const int nbEs = (ESTRIDE + 255) / 256;  // 586

  k_prep<<<nbN, 256, 0, stream>>>(EI, W, flag, cnt, Wb);
  k_gemm<<<(NN + 127) / 128, 256, 0, stream>>>(X, Wb, AL, AR, emb, sl, sr);
  k_hist<<<nbEs, 256, 0, stream>>>(EI, flag, cnt);
  k_scanA<<<nbN, 256, 0, stream>>>(cnt, offs, bsum);
  k_scanB<<<1, 256, 0, stream>>>(bsum, nbN);
  k_scanC<<<nbN, 256, 0, stream>>>(bsum, offs, cur);
  k_scatter<<<nbEs, 256, 0, stream>>>(EI, flag, cur, ssrc);
  k_agg<<<(NN * 64 + 255) / 256, 256, 0, stream>>>(emb, sl, sr, offs, ssrc, B, out);
}

// Round 7
// 127.155 us; speedup vs baseline: 1.9862x; 1.0407x over previous
//
#include <hip/hip_runtime.h>

#define NN 50000
#define EE 600000
#define CC 128
#define HH 8
#define ESTRIDE 150000   // EE/4: edges per grid-stride pass (scatter)
#define GB 391           // gemm blocks = ceil(NN/128)
#define EPB 1535         // edges per gemm block for fused hist (391*1535 >= EE)
#define LOG2E 1.4426950408889634f

typedef unsigned int u32;
typedef unsigned short u16;
typedef __attribute__((ext_vector_type(8))) short short8;
typedef __attribute__((ext_vector_type(4))) float f32x4;

__device__ __forceinline__ float b2f(u32 u) { return __uint_as_float(u << 16); }
__device__ __forceinline__ u16 f2b(float f) {
  u32 x = __float_as_uint(f);
  return (u16)((x + 0x7fffu + ((x >> 16) & 1u)) >> 16);
}

// workspace layout in 4-byte words
enum : int {
  OFF_FLAG = 0,
  OFF_CNT  = 64,
  OFF_OFFS = OFF_CNT + NN,
  OFF_CUR  = OFF_OFFS + NN + 64,
  OFF_BSUM = OFF_CUR + NN,          // 256 words
  OFF_WB   = OFF_BSUM + 256,        // 8192 words: bf16 W[128][128]
  OFF_SL   = OFF_WB + 8192,
  OFF_SR   = OFF_SL + NN * HH,
  OFF_SSRC = OFF_SR + NN * HH,      // u16 ssrc: EE/2 words
  OFF_EMB  = OFF_SSRC + EE / 2 + 64,
  WS_WORDS = OFF_EMB + NN * 64
};

// ---- prep: zero cnt, convert W->bf16, sniff edge dtype --------------------
__global__ __launch_bounds__(256) void k_prep(const int* __restrict__ ei, const float* __restrict__ W,
                                              int* __restrict__ flag, int* __restrict__ cnt,
                                              u32* __restrict__ Wb) {
  int i = blockIdx.x * 256 + threadIdx.x;
  if (i < NN) cnt[i] = 0;
  if (i < CC * CC / 2) {
    float2 v = ((const float2*)W)[i];
    Wb[i] = (u32)f2b(v.x) | ((u32)f2b(v.y) << 16);
  }
  if (blockIdx.x == 0) {
    __shared__ int any;
    if (threadIdx.x == 0) any = 0;
    __syncthreads();
    int nz = 0;
    for (int k = threadIdx.x; k < 1024; k += 256) nz |= (ei[2 * k + 1] != 0) ? 1 : 0;
    if (nz) any = 1;  // benign race
    __syncthreads();
    if (threadIdx.x == 0) flag[0] = any;  // 1 => int32 layout, 0 => int64 layout
  }
}

// ---- MFMA bf16 GEMM, BM=128, fused scores + fused edge histogram ----------
#define WS_BASE 0              // bf16 W[128][128], 32 KB, XOR-swizzled
#define XS_BASE 32768          // bf16 X-tile[128][128], 32 KB, XOR-swizzled (reused for out-stage)
__device__ __forceinline__ int swz(int row, int byte_in_row) {
  return ((row * 256 + byte_in_row) ^ ((row & 7) << 4));
}

__global__ __launch_bounds__(256) void k_gemm(const float* __restrict__ X,
                                              const u32* __restrict__ Wb,
                                              const float* __restrict__ al,
                                              const float* __restrict__ ar,
                                              const int* __restrict__ ei,
                                              const int* __restrict__ flag,
                                              int* __restrict__ cnt,
                                              u32* __restrict__ emb,
                                              float* __restrict__ sl, float* __restrict__ sr) {
  __shared__ unsigned char lds[65536];
  const int tid = threadIdx.x;
  const int n0 = blockIdx.x * 128;
  const int lane = tid & 63;
  const int w = tid >> 6;
  const int cwh16 = lane & 15, kg = lane >> 4;

  // fused histogram: this block's edge slice (atomic latency hides under GEMM)
  {
    const int f = flag[0];
    const int ebase = blockIdx.x * EPB;
    const int eend = (ebase + EPB < EE) ? ebase + EPB : EE;
    for (int e = ebase + tid; e < eend; e += 256) {
      int t = f ? ei[EE + e] : ((const int2*)ei)[EE + e].x;
      atomicAdd(&cnt[t], 1);
    }
  }

  // stage W (already bf16): 2048 x 16B pure copies
#pragma unroll
  for (int i = 0; i < 8; ++i) {
    int idx = tid + i * 256;
    int r = idx >> 4, c16 = idx & 15;
    uint4 v = ((const uint4*)Wb)[idx];
    *(uint4*)&lds[WS_BASE + swz(r, c16 * 16)] = v;
  }
  // stage X tile (f32 -> bf16): 128 rows x 32 float4
#pragma unroll
  for (int i = 0; i < 16; ++i) {
    int idx = tid + i * 256;
    int r = idx >> 5, c4 = idx & 31;
    int n = n0 + r;
    float4 v = make_float4(0.f, 0.f, 0.f, 0.f);
    if (n < NN) v = ((const float4*)X)[n * 32 + c4];
    u32 p0 = (u32)f2b(v.x) | ((u32)f2b(v.y) << 16);
    u32 p1 = (u32)f2b(v.z) | ((u32)f2b(v.w) << 16);
    *(uint2*)&lds[XS_BASE + swz(r, c4 * 8)] = make_uint2(p0, p1);
  }
  __syncthreads();

  f32x4 acc[2][8];
#pragma unroll
  for (int rt = 0; rt < 2; ++rt)
#pragma unroll
    for (int nt = 0; nt < 8; ++nt) acc[rt][nt] = (f32x4){0.f, 0.f, 0.f, 0.f};

#pragma unroll
  for (int kk = 0; kk < 4; ++kk) {
    const int kb = kk * 64 + kg * 16;
    short8 a0 = *(const short8*)&lds[XS_BASE + swz(w * 32 + cwh16, kb)];
    short8 a1 = *(const short8*)&lds[XS_BASE + swz(w * 32 + 16 + cwh16, kb)];
#pragma unroll
    for (int nt = 0; nt < 8; ++nt) {
      short8 b = *(const short8*)&lds[WS_BASE + swz(nt * 16 + cwh16, kb)];
      acc[0][nt] = __builtin_amdgcn_mfma_f32_16x16x32_bf16(a0, b, acc[0][nt], 0, 0, 0);
      acc[1][nt] = __builtin_amdgcn_mfma_f32_16x16x32_bf16(a1, b, acc[1][nt], 0, 0, 0);
    }
  }

  // store accumulators to LDS (bf16, swizzled) — wave w owns rows w*32..w*32+31
  __syncthreads();
#pragma unroll
  for (int rt = 0; rt < 2; ++rt)
#pragma unroll
    for (int nt = 0; nt < 8; ++nt) {
      const int col = nt * 16 + cwh16;
#pragma unroll
      for (int reg = 0; reg < 4; ++reg) {
        const int r = w * 32 + rt * 16 + kg * 4 + reg;
        *(u16*)&lds[XS_BASE + swz(r, col * 2)] = f2b(acc[rt][nt][reg]);
      }
    }
  __syncthreads();

  // fused scores from LDS emb tile (pre-scaled by log2(e) for exp2 in k_agg)
#pragma unroll
  for (int sc = 0; sc < 2; ++sc) {
    int tidx = tid + sc * 256;           // 0..511
    int r = tidx >> 2, hp = tidx & 3;
    int n = n0 + r;
    if (n < NN) {
      float sAl = 0.f, sAr = 0.f, sBl = 0.f, sBr = 0.f;
#pragma unroll
      for (int j = 0; j < 2; ++j) {      // head 2hp, cwh j*8..j*8+7
        uint4 q = *(const uint4*)&lds[XS_BASE + swz(r, hp * 64 + j * 16)];
        u32 qq[4] = {q.x, q.y, q.z, q.w};
        const int h = 2 * hp;
#pragma unroll
        for (int u = 0; u < 4; ++u) {
          int cwh = j * 8 + 2 * u;
          float lo = b2f(qq[u] & 0xffffu), hi = b2f(qq[u] >> 16);
          sAl = fmaf(lo, al[cwh * 8 + h], sAl);       sAr = fmaf(lo, ar[cwh * 8 + h], sAr);
          sAl = fmaf(hi, al[(cwh + 1) * 8 + h], sAl); sAr = fmaf(hi, ar[(cwh + 1) * 8 + h], sAr);
        }
      }
#pragma unroll
      for (int j = 0; j < 2; ++j) {      // head 2hp+1
        uint4 q = *(const uint4*)&lds[XS_BASE + swz(r, hp * 64 + 32 + j * 16)];
        u32 qq[4] = {q.x, q.y, q.z, q.w};
        const int h = 2 * hp + 1;
#pragma unroll
        for (int u = 0; u < 4; ++u) {
          int cwh = j * 8 + 2 * u;
          float lo = b2f(qq[u] & 0xffffu), hi = b2f(qq[u] >> 16);
          sBl = fmaf(lo, al[cwh * 8 + h], sBl);       sBr = fmaf(lo, ar[cwh * 8 + h], sBr);
          sBl = fmaf(hi, al[(cwh + 1) * 8 + h], sBl); sBr = fmaf(hi, ar[(cwh + 1) * 8 + h], sBr);
        }
      }
      ((float2*)&sl[n * HH])[hp] = make_float2(sAl * LOG2E, sBl * LOG2E);
      ((float2*)&sr[n * HH])[hp] = make_float2(sAr * LOG2E, sBr * LOG2E);
    }
  }

  // emb global write: 2048 x 16B coalesced
#pragma unroll
  for (int i = 0; i < 8; ++i) {
    int idx = tid + i * 256;
    int r = idx >> 4, c16 = idx & 15;
    int n = n0 + r;
    if (n < NN) {
      uint4 v = *(const uint4*)&lds[XS_BASE + swz(r, c16 * 16)];
      *((uint4*)(emb + n * 64 + c16 * 4)) = v;
    }
  }
}

// ---- CSR scan chain -------------------------------------------------------
__global__ __launch_bounds__(256) void k_scanA(const int* __restrict__ cnt, int* __restrict__ offs,
                                               int* __restrict__ bsum) {
  __shared__ int tmp[256];
  const int t = threadIdx.x;
  const int i = blockIdx.x * 256 + t;
  int v = (i < NN) ? cnt[i] : 0;
  tmp[t] = v;
  __syncthreads();
#pragma unroll
  for (int d = 1; d < 256; d <<= 1) {
    int x = (t >= d) ? tmp[t - d] : 0;
    __syncthreads();
    tmp[t] += x;
    __syncthreads();
  }
  if (i < NN) offs[i] = tmp[t] - v;      // block-local exclusive
  if (t == 255) bsum[blockIdx.x] = tmp[255];
}

__global__ __launch_bounds__(256) void k_scanB(int* __restrict__ bsum, int nb) {
  __shared__ int tmp[256];
  const int t = threadIdx.x;
  int v = (t < nb) ? bsum[t] : 0;
  tmp[t] = v;
  __syncthreads();
#pragma unroll
  for (int d = 1; d < 256; d <<= 1) {
    int x = (t >= d) ? tmp[t - d] : 0;
    __syncthreads();
    tmp[t] += x;
    __syncthreads();
  }
  if (t < nb) bsum[t] = tmp[t] - v;      // exclusive
}

__global__ __launch_bounds__(256) void k_scanC(const int* __restrict__ bsum, int* __restrict__ offs,
                                               int* __restrict__ cur) {
  const int i = blockIdx.x * 256 + threadIdx.x;
  if (i < NN) {
    int o = offs[i] + bsum[blockIdx.x];
    offs[i] = o;
    cur[i] = o;
  }
  if (i == 0) offs[NN] = EE;
}

__global__ __launch_bounds__(256) void k_scatter(const int* __restrict__ ei, const int* __restrict__ flag,
                                                 int* __restrict__ cur, u16* __restrict__ ssrc) {
  const int tid = blockIdx.x * 256 + threadIdx.x;
  if (tid >= ESTRIDE) return;
  const int f = flag[0];
  int s[4], t[4];
  if (f) {
#pragma unroll
    for (int k = 0; k < 4; ++k) {
      s[k] = ei[tid + k * ESTRIDE];
      t[k] = ei[EE + tid + k * ESTRIDE];
    }
  } else {
#pragma unroll
    for (int k = 0; k < 4; ++k) {
      s[k] = ((const int2*)ei)[tid + k * ESTRIDE].x;
      t[k] = ((const int2*)ei)[EE + tid + k * ESTRIDE].x;
    }
  }
  int pos[4];
#pragma unroll
  for (int k = 0; k < 4; ++k) pos[k] = atomicAdd(&cur[t[k]], 1);
#pragma unroll
  for (int k = 0; k < 4; ++k) ssrc[pos[k]] = (u16)s[k];
}

// ---- single-pass aggregation, predicated 8-wide ---------------------------
__global__ __launch_bounds__(256) void k_agg(const u32* __restrict__ emb,
                                             const float* __restrict__ sl, const float* __restrict__ sr,
                                             const int* __restrict__ offs, const u16* __restrict__ ssrc,
                                             const float* __restrict__ bias, float* __restrict__ out) {
  const int t = (blockIdx.x * 256 + threadIdx.x) >> 6;
  const int lane = threadIdx.x & 63;
  if (t >= NN) return;
  const int e0 = offs[t], e1 = offs[t + 1];
  const int h2 = lane >> 3;
  const float sr2 = sr[t * HH + h2];
  float ax = 0.f, ay = 0.f, den = 0.f;
  for (int e = e0; e < e1; e += 8) {
    int s[8];
#pragma unroll
    for (int k = 0; k < 8; ++k) {
      int idx = (e + k < e1) ? e + k : e0;
      s[k] = (int)ssrc[idx];
    }
    float v[8];
    u32 p[8];
#pragma unroll
    for (int k = 0; k < 8; ++k) v[k] = sl[s[k] * HH + h2];
#pragma unroll
    for (int k = 0; k < 8; ++k) p[k] = emb[s[k] * 64 + lane];
#pragma unroll
    for (int k = 0; k < 8; ++k) {
      float vv = v[k] + sr2;
      vv = (vv > 0.f) ? vv : 0.2f * vv;
      float wgt = exp2f(vv);                 // scores pre-scaled by log2(e)
      wgt = (e + k < e1) ? wgt : 0.f;
      den += wgt;
      ax = fmaf(wgt, b2f(p[k] & 0xffffu), ax);
      ay = fmaf(wgt, b2f(p[k] >> 16), ay);
    }
  }
  const float inv = 1.f / (den + 1e-16f);
  float2 bv = ((const float2*)bias)[lane];
  ((float2*)out)[t * 64 + lane] = make_float2(fmaf(ax, inv, bv.x), fmaf(ay, inv, bv.y));
}

extern "C" void kernel_launch(void* const* d_in, const int* in_sizes, int n_in,
                              void* d_out, int out_size, void* d_ws, size_t ws_size,
                              hipStream_t stream) {
  const float* X  = (const float*)d_in[0];
  const int*   EI = (const int*)d_in[1];
  const float* W  = (const float*)d_in[2];
  const float* AL = (const float*)d_in[3];
  const float* AR = (const float*)d_in[4];
  const float* B  = (const float*)d_in[5];
  float* out = (float*)d_out;
  u32* ws = (u32*)d_ws;

  int*   flag = (int*)(ws + OFF_FLAG);
  int*   cnt  = (int*)(ws + OFF_CNT);
  int*   offs = (int*)(ws + OFF_OFFS);
  int*   cur  = (int*)(ws + OFF_CUR);
  int*   bsum = (int*)(ws + OFF_BSUM);
  u32*   Wb   = (u32*)(ws + OFF_WB);
  float* sl   = (float*)(ws + OFF_SL);
  float* sr   = (float*)(ws + OFF_SR);
  u16*   ssrc = (u16*)(ws + OFF_SSRC);
  u32*   emb  = (u32*)(ws + OFF_EMB);

  const int nbN = (NN + 255) / 256;        // 196
  const int nbEs = (ESTRIDE + 255) / 256;  // 586

  k_prep<<<nbN, 256, 0, stream>>>(EI, W, flag, cnt, Wb);
  k_gemm<<<GB, 256, 0, stream>>>(X, Wb, AL, AR, EI, flag, cnt, emb, sl, sr);
  k_scanA<<<nbN, 256, 0, stream>>>(cnt, offs, bsum);
  k_scanB<<<1, 256, 0, stream>>>(bsum, nbN);
  k_scanC<<<nbN, 256, 0, stream>>>(bsum, offs, cur);
  k_scatter<<<nbEs, 256, 0, stream>>>(EI, flag, cur, ssrc);
  k_agg<<<(NN * 64 + 255) / 256, 256, 0, stream>>>(emb, sl, sr, offs, ssrc, B, out);
}